// Round 1
// baseline (6521.690 us; speedup 1.0000x reference)
//
#include <hip/hip_runtime.h>
#include <hip/hip_bf16.h>

// Problem constants (fixed by the reference)
#define N_ 100000
#define E_ 400000
#define B_ 2048
#define H_ 300
#define L_ 5
#define NT_ 120
#define EF_ 16
#define T_ 128
#define BNS 0.9999950000374997f  // 1/sqrt(1+1e-5)

// ---------------- CSR build ----------------
__global__ void k_hist(const int* __restrict__ dst, int* __restrict__ degi, int E) {
    int e = blockIdx.x * blockDim.x + threadIdx.x;
    if (e < E) atomicAdd(&degi[dst[e]], 1);
}

__global__ void k_norm(const int* __restrict__ degi, float* __restrict__ nrm,
                       float* __restrict__ invdeg, int N) {
    int n = blockIdx.x * blockDim.x + threadIdx.x;
    if (n < N) {
        float d = (float)degi[n] + 1.0f;
        nrm[n] = 1.0f / sqrtf(d);
        invdeg[n] = 1.0f / d;
    }
}

__global__ void k_scan1(const int* __restrict__ in, int* __restrict__ out,
                        int* __restrict__ partial, int N) {
    __shared__ int s[1024];
    int i = blockIdx.x * 1024 + threadIdx.x;
    int v = (i < N) ? in[i] : 0;
    s[threadIdx.x] = v;
    __syncthreads();
    for (int off = 1; off < 1024; off <<= 1) {
        int t = (threadIdx.x >= off) ? s[threadIdx.x - off] : 0;
        __syncthreads();
        s[threadIdx.x] += t;
        __syncthreads();
    }
    if (i < N) out[i] = s[threadIdx.x] - v;  // exclusive
    if (threadIdx.x == 1023) partial[blockIdx.x] = s[1023];
}

__global__ void k_scan2(int* __restrict__ partial, int nb, int* __restrict__ totalOut) {
    if (blockIdx.x == 0 && threadIdx.x == 0) {
        int run = 0;
        for (int i = 0; i < nb; i++) { int v = partial[i]; partial[i] = run; run += v; }
        *totalOut = run;
    }
}

__global__ void k_scan3(int* __restrict__ out, const int* __restrict__ partial, int N) {
    int i = blockIdx.x * 1024 + threadIdx.x;
    if (i < N) out[i] += partial[blockIdx.x];
}

__global__ void k_scatter(const int* __restrict__ dst, int* __restrict__ cursor,
                          int* __restrict__ eid, int E) {
    int e = blockIdx.x * blockDim.x + threadIdx.x;
    if (e < E) {
        int d = dst[e];
        int pos = atomicAdd(&cursor[d], 1);
        eid[pos] = e;
    }
}

__global__ void k_rowstart(const int* __restrict__ gid, int* __restrict__ rs, int N, int B) {
    int b = blockIdx.x * blockDim.x + threadIdx.x;
    if (b <= B) {
        int lo = 0, hi = N;
        while (lo < hi) { int mid = (lo + hi) >> 1; if (gid[mid] < b) lo = mid + 1; else hi = mid; }
        rs[b] = lo;
    }
}

// ---------------- init ----------------
__global__ void k_hinit(const int* __restrict__ nt, const float* __restrict__ emb,
                        const float* __restrict__ vn_emb, float* __restrict__ h) {
    int n = blockIdx.x; int j = threadIdx.x;
    if (j >= H_) return;
    h[(size_t)n * H_ + j] = emb[(size_t)nt[n] * H_ + j] + vn_emb[j];
}

__global__ void k_vninit(const float* __restrict__ vn_emb, float* __restrict__ vn) {
    int b = blockIdx.x; int j = threadIdx.x;
    if (j >= H_) return;
    vn[(size_t)b * H_ + j] = vn_emb[j];
}

// ---------------- generic fp32 GEMM with fused epilogue ----------------
// C[M,Nn] = maybe_relu( (A[M,K]@Bm[K,Nn] + bias) * (scale*BNS) + shift )
#define GBM 128
#define GBN 64
#define GBK 16
__launch_bounds__(256)
__global__ void k_gemm(const float* __restrict__ A, const float* __restrict__ Bm,
                       float* __restrict__ C, int M, int Nn, int K,
                       const float* __restrict__ bias, const float* __restrict__ scale,
                       const float* __restrict__ shift, int relu) {
    __shared__ float As[GBM][GBK + 1];
    __shared__ float Bs[GBK][GBN];
    int tid = threadIdx.x;
    int tx = tid & 15, ty = tid >> 4;
    int m0 = blockIdx.x * GBM, n0 = blockIdx.y * GBN;
    float acc[8][4];
    #pragma unroll
    for (int i = 0; i < 8; i++)
        #pragma unroll
        for (int j = 0; j < 4; j++) acc[i][j] = 0.f;

    for (int k0 = 0; k0 < K; k0 += GBK) {
        #pragma unroll
        for (int i = 0; i < 8; i++) {
            int li = tid + i * 256;
            int r = li >> 4, c = li & 15;
            int gm = m0 + r, gk = k0 + c;
            As[r][c] = (gm < M && gk < K) ? A[(size_t)gm * K + gk] : 0.f;
        }
        #pragma unroll
        for (int i = 0; i < 4; i++) {
            int li = tid + i * 256;
            int r = li >> 6, c = li & 63;
            int gk = k0 + r, gn = n0 + c;
            Bs[r][c] = (gk < K && gn < Nn) ? Bm[(size_t)gk * Nn + gn] : 0.f;
        }
        __syncthreads();
        #pragma unroll
        for (int k = 0; k < GBK; k++) {
            float4 b4 = *reinterpret_cast<const float4*>(&Bs[k][4 * tx]);
            #pragma unroll
            for (int i = 0; i < 8; i++) {
                float a = As[ty + 16 * i][k];
                acc[i][0] += a * b4.x;
                acc[i][1] += a * b4.y;
                acc[i][2] += a * b4.z;
                acc[i][3] += a * b4.w;
            }
        }
        __syncthreads();
    }
    #pragma unroll
    for (int i = 0; i < 8; i++) {
        int gm = m0 + ty + 16 * i;
        if (gm >= M) continue;
        #pragma unroll
        for (int j = 0; j < 4; j++) {
            int gn = n0 + 4 * tx + j;
            if (gn >= Nn) continue;
            float v = acc[i][j];
            if (bias) v += bias[gn];
            if (scale) v = v * (scale[gn] * BNS) + shift[gn];
            if (relu) v = fmaxf(v, 0.f);
            C[(size_t)gm * Nn + gn] = v;
        }
    }
}

// ---------------- per-graph segment sums ----------------
__global__ void k_vtmp(const float* __restrict__ h, const float* __restrict__ vn,
                       const int* __restrict__ rs, float* __restrict__ vtmp) {
    int b = blockIdx.x; int j = threadIdx.x;
    if (j >= H_) return;
    int s = rs[b], e = rs[b + 1];
    float acc = 0.f;
    for (int n = s; n < e; n++) acc += h[(size_t)n * H_ + j];
    vtmp[(size_t)b * H_ + j] = acc + vn[(size_t)b * H_ + j];
}

__global__ void k_gmean(const float* __restrict__ h, const int* __restrict__ rs,
                        float* __restrict__ gm) {
    int b = blockIdx.x; int j = threadIdx.x;
    if (j >= H_) return;
    int s = rs[b], e = rs[b + 1];
    float acc = 0.f;
    for (int n = s; n < e; n++) acc += h[(size_t)n * H_ + j];
    int cnt = e - s; if (cnt < 1) cnt = 1;
    gm[(size_t)b * H_ + j] = acc / (float)cnt;
}

// ---------------- edge aggregation + epilogue (writes h in place) ----------------
__global__ void k_agg(const float* __restrict__ x, float* __restrict__ h,
                      const int* __restrict__ off, const int* __restrict__ eid,
                      const int* __restrict__ src, const float* __restrict__ ef,
                      const float* __restrict__ We_l, const float* __restrict__ be_l,
                      const float* __restrict__ nrm, const float* __restrict__ invdeg,
                      const float* __restrict__ root_l, const float* __restrict__ gamma_l,
                      const float* __restrict__ beta_l,
                      const float* __restrict__ vn_next, const int* __restrict__ gid,
                      int relu) {
    int n = blockIdx.x; int j = threadIdx.x;
    if (j >= H_) return;
    int s = off[n], e = off[n + 1];
    float nrm_n = nrm[n];
    float bej = be_l[j];
    float acc = 0.f;
    for (int idx = s; idx < e; idx++) {
        int ed = eid[idx];
        int sn = src[ed];
        float en = nrm_n * nrm[sn];
        float ev = bej;
        #pragma unroll
        for (int k = 0; k < EF_; k++) ev += ef[(size_t)ed * EF_ + k] * We_l[k * H_ + j];
        float msg = x[(size_t)sn * H_ + j] + ev;
        acc += en * fmaxf(msg, 0.f);
    }
    float v = acc + fmaxf(x[(size_t)n * H_ + j] + root_l[j], 0.f) * invdeg[n];
    v = v * (gamma_l[j] * BNS) + beta_l[j];
    if (relu) v = fmaxf(v, 0.f);
    if (vn_next) v += vn_next[(size_t)gid[n] * H_ + j];
    h[(size_t)n * H_ + j] = v;
}

// ---------------- launch ----------------
extern "C" void kernel_launch(void* const* d_in, const int* in_sizes, int n_in,
                              void* d_out, int out_size, void* d_ws, size_t ws_size,
                              hipStream_t stream) {
    const int* node_types = (const int*)d_in[0];
    const int* src        = (const int*)d_in[1];
    const int* dst        = (const int*)d_in[2];
    const int* graph_ids  = (const int*)d_in[3];
    const float* edge_feats = (const float*)d_in[4];
    const float* node_emb   = (const float*)d_in[5];
    const float* Wn   = (const float*)d_in[6];
    const float* bn   = (const float*)d_in[7];
    const float* We   = (const float*)d_in[8];
    const float* be   = (const float*)d_in[9];
    const float* root = (const float*)d_in[10];
    const float* gamma = (const float*)d_in[11];
    const float* beta  = (const float*)d_in[12];
    const float* vn_emb = (const float*)d_in[13];
    const float* W1  = (const float*)d_in[14];
    const float* b1  = (const float*)d_in[15];
    const float* g1  = (const float*)d_in[16];
    const float* be1 = (const float*)d_in[17];
    const float* W2  = (const float*)d_in[18];
    const float* b2  = (const float*)d_in[19];
    const float* g2  = (const float*)d_in[20];
    const float* be2 = (const float*)d_in[21];
    const float* pW  = (const float*)d_in[22];
    const float* pb  = (const float*)d_in[23];
    float* out = (float*)d_out;

    // workspace carve-up
    char* p = (char*)d_ws;
    auto alloc = [&](size_t bytes) { void* q = (void*)p; p += (bytes + 255) & ~(size_t)255; return q; };
    const size_t NH = (size_t)N_ * H_;
    float* h     = (float*)alloc(NH * 4);
    float* x     = (float*)alloc(NH * 4);
    float* vn    = (float*)alloc((size_t)B_ * H_ * 4);
    float* vtmp  = (float*)alloc((size_t)B_ * H_ * 4);
    float* z     = (float*)alloc((size_t)B_ * 2 * H_ * 4);
    float* nrm   = (float*)alloc((size_t)N_ * 4);
    float* invdeg= (float*)alloc((size_t)N_ * 4);
    int* degi    = (int*)alloc((size_t)N_ * 4);
    int* csr_off = (int*)alloc((size_t)(N_ + 1) * 4);
    int* cursor  = (int*)alloc((size_t)N_ * 4);
    int* csr_eid = (int*)alloc((size_t)E_ * 4);
    int* rs      = (int*)alloc((size_t)(B_ + 1) * 4);
    int* partial = (int*)alloc((size_t)128 * 4);

    const int SCAN_NB = (N_ + 1023) / 1024;  // 98

    // degree histogram + norms
    hipMemsetAsync(degi, 0, (size_t)N_ * 4, stream);
    k_hist<<<(E_ + 255) / 256, 256, 0, stream>>>(dst, degi, E_);
    k_norm<<<(N_ + 255) / 256, 256, 0, stream>>>(degi, nrm, invdeg, N_);

    // CSR offsets = exclusive scan of degi
    k_scan1<<<SCAN_NB, 1024, 0, stream>>>(degi, csr_off, partial, N_);
    k_scan2<<<1, 1, 0, stream>>>(partial, SCAN_NB, csr_off + N_);
    k_scan3<<<SCAN_NB, 1024, 0, stream>>>(csr_off, partial, N_);
    hipMemcpyAsync(cursor, csr_off, (size_t)N_ * 4, hipMemcpyDeviceToDevice, stream);
    k_scatter<<<(E_ + 255) / 256, 256, 0, stream>>>(dst, cursor, csr_eid, E_);

    // graph segment boundaries (graph_ids sorted)
    k_rowstart<<<(B_ + 1 + 255) / 256, 256, 0, stream>>>(graph_ids, rs, N_, B_);

    // h = node_emb[nt] + vn_emb (layer-0 vn broadcast fused); vn = vn_emb
    k_hinit<<<N_, 320, 0, stream>>>(node_types, node_emb, vn_emb, h);
    k_vninit<<<B_, 320, 0, stream>>>(vn_emb, vn);

    dim3 gx((N_ + GBM - 1) / GBM, (H_ + GBN - 1) / GBN);       // 782 x 5
    dim3 gm1((B_ + GBM - 1) / GBM, (2 * H_ + GBN - 1) / GBN);  // 16 x 10
    dim3 gm2((B_ + GBM - 1) / GBM, (H_ + GBN - 1) / GBN);      // 16 x 5
    dim3 gh((B_ + GBM - 1) / GBM, (T_ + GBN - 1) / GBN);       // 16 x 2

    for (int l = 0; l < L_; l++) {
        // x = h @ Wn[l] + bn[l]
        k_gemm<<<gx, 256, 0, stream>>>(h, Wn + (size_t)l * H_ * H_, x, N_, H_, H_,
                                       bn + (size_t)l * H_, nullptr, nullptr, 0);
        if (l < L_ - 1) {
            // vtmp = segsum(h) + vn ; z = relu(bn1(vtmp@W1+b1)) ; vn = relu(bn2(z@W2+b2))
            k_vtmp<<<B_, 320, 0, stream>>>(h, vn, rs, vtmp);
            k_gemm<<<gm1, 256, 0, stream>>>(vtmp, W1 + (size_t)l * H_ * 2 * H_, z,
                                            B_, 2 * H_, H_,
                                            b1 + (size_t)l * 2 * H_,
                                            g1 + (size_t)l * 2 * H_,
                                            be1 + (size_t)l * 2 * H_, 1);
            k_gemm<<<gm2, 256, 0, stream>>>(z, W2 + (size_t)l * 2 * H_ * H_, vn,
                                            B_, H_, 2 * H_,
                                            b2 + (size_t)l * H_,
                                            g2 + (size_t)l * H_,
                                            be2 + (size_t)l * H_, 1);
        }
        // h = bn(agg + relu(x+root)*invdeg) (+relu if l<L-1) (+vn_next[gid] if l<L-1)
        k_agg<<<N_, 320, 0, stream>>>(x, h, csr_off, csr_eid, src, edge_feats,
                                      We + (size_t)l * EF_ * H_, be + (size_t)l * H_,
                                      nrm, invdeg,
                                      root + (size_t)l * H_,
                                      gamma + (size_t)l * H_, beta + (size_t)l * H_,
                                      (l < L_ - 1) ? vn : nullptr, graph_ids,
                                      (l < L_ - 1) ? 1 : 0);
    }

    // readout: gmean -> head
    k_gmean<<<B_, 320, 0, stream>>>(h, rs, vtmp);
    k_gemm<<<gh, 256, 0, stream>>>(vtmp, pW, out, B_, T_, H_, pb, nullptr, nullptr, 0);
}

// Round 3
// 3286.464 us; speedup vs baseline: 1.9844x; 1.9844x over previous
//
#include <hip/hip_runtime.h>
#include <hip/hip_bf16.h>

// Problem constants (fixed by the reference)
#define N_ 100000
#define MPAD 100096          // 782 * 128
#define E_ 400000
#define B_ 2048
#define H_ 300
#define KP_ 320              // K padded to mult of 32
#define NPB 384              // padded output-col rows of W^T (3 * 128)
#define L_ 5
#define EF_ 16
#define T_ 128
#define BNS 0.9999950000374997f  // 1/sqrt(1+1e-5)

typedef unsigned short ushort_t;
typedef short bf16x8 __attribute__((ext_vector_type(8)));
typedef float f32x4 __attribute__((ext_vector_type(4)));

__device__ __forceinline__ ushort_t f2b(float v) {
    unsigned u = __float_as_uint(v);
    unsigned r = (u + 0x7FFFu + ((u >> 16) & 1u)) >> 16;
    return (ushort_t)r;
}

__device__ __forceinline__ float b2f(ushort_t u) {
    return __uint_as_float(((unsigned)u) << 16);
}

__device__ __forceinline__ void gl_lds16(const void* g, void* l) {
    __builtin_amdgcn_global_load_lds(
        (const __attribute__((address_space(1))) void*)g,
        (__attribute__((address_space(3))) void*)l, 16, 0, 0);
}

// ---------------- CSR build ----------------
__global__ void k_hist(const int* __restrict__ dst, int* __restrict__ degi, int E) {
    int e = blockIdx.x * blockDim.x + threadIdx.x;
    if (e < E) atomicAdd(&degi[dst[e]], 1);
}

__global__ void k_norm(const int* __restrict__ degi, float* __restrict__ nrm,
                       float* __restrict__ invdeg, int N) {
    int n = blockIdx.x * blockDim.x + threadIdx.x;
    if (n < N) {
        float d = (float)degi[n] + 1.0f;
        nrm[n] = 1.0f / sqrtf(d);
        invdeg[n] = 1.0f / d;
    }
}

__global__ void k_scan1(const int* __restrict__ in, int* __restrict__ out,
                        int* __restrict__ partial, int N) {
    __shared__ int s[1024];
    int i = blockIdx.x * 1024 + threadIdx.x;
    int v = (i < N) ? in[i] : 0;
    s[threadIdx.x] = v;
    __syncthreads();
    for (int off = 1; off < 1024; off <<= 1) {
        int t = (threadIdx.x >= off) ? s[threadIdx.x - off] : 0;
        __syncthreads();
        s[threadIdx.x] += t;
        __syncthreads();
    }
    if (i < N) out[i] = s[threadIdx.x] - v;  // exclusive
    if (threadIdx.x == 1023) partial[blockIdx.x] = s[1023];
}

__global__ void k_scan2(int* __restrict__ partial, int nb, int* __restrict__ totalOut) {
    if (blockIdx.x == 0 && threadIdx.x == 0) {
        int run = 0;
        for (int i = 0; i < nb; i++) { int v = partial[i]; partial[i] = run; run += v; }
        *totalOut = run;
    }
}

__global__ void k_scan3(int* __restrict__ out, const int* __restrict__ partial, int N) {
    int i = blockIdx.x * 1024 + threadIdx.x;
    if (i < N) out[i] += partial[blockIdx.x];
}

__global__ void k_scatter(const int* __restrict__ dst, const int* __restrict__ src,
                          int* __restrict__ cursor, int* __restrict__ eid,
                          int* __restrict__ csrc, int E) {
    int e = blockIdx.x * blockDim.x + threadIdx.x;
    if (e < E) {
        int d = dst[e];
        int pos = atomicAdd(&cursor[d], 1);
        eid[pos] = e;
        csrc[pos] = src[e];
    }
}

__global__ void k_rowstart(const int* __restrict__ gid, int* __restrict__ rs, int N, int B) {
    int b = blockIdx.x * blockDim.x + threadIdx.x;
    if (b <= B) {
        int lo = 0, hi = N;
        while (lo < hi) { int mid = (lo + hi) >> 1; if (gid[mid] < b) lo = mid + 1; else hi = mid; }
        rs[b] = lo;
    }
}

// ---------------- init ----------------
__global__ void k_hinit(const int* __restrict__ nt, const float* __restrict__ emb,
                        const float* __restrict__ vn_emb,
                        ushort_t* __restrict__ h_bf) {
    int n = blockIdx.x; int j = threadIdx.x;
    if (j >= H_) return;
    float v = emb[(size_t)nt[n] * H_ + j] + vn_emb[j];
    int u = ((j >> 3) & 3) ^ ((n >> 1) & 3);
    int col = (j & ~31) | (u << 3) | (j & 7);
    h_bf[(size_t)n * KP_ + col] = f2b(v);
}

__global__ void k_vninit(const float* __restrict__ vn_emb, float* __restrict__ vn) {
    int b = blockIdx.x; int j = threadIdx.x;
    if (j >= H_) return;
    vn[(size_t)b * H_ + j] = vn_emb[j];
}

// W^T conversion: WnT[l][n][k] = Wn[l][k][n], bf16, zero-padded, 16B-unit swizzled per row
__global__ void k_convWnT(const float* __restrict__ Wn, ushort_t* __restrict__ WnT) {
    const int UPR = KP_ / 8;  // 40 units per row
    int idx = blockIdx.x * 256 + threadIdx.x;
    if (idx >= L_ * NPB * UPR) return;
    int l = idx / (NPB * UPR); int r = idx % (NPB * UPR);
    int n = r / UPR; int ku = r % UPR;
    int k0 = ku * 8;
    int swz = (ku & 3) ^ ((n >> 1) & 3);
    size_t dst = ((size_t)l * NPB + n) * KP_ + (size_t)(k0 & ~31) + swz * 8;
    #pragma unroll
    for (int i = 0; i < 8; i++) {
        int k = k0 + i;
        float v = (k < H_ && n < H_) ? Wn[((size_t)l * H_ + k) * H_ + n] : 0.f;
        WnT[dst + i] = f2b(v);
    }
}

// ---------------- bf16 MFMA GEMM: C[M,Nn] = A[M,KP_] @ B[KP_,Nn] + bias ----------------
// A: swizzled bf16 [>=M rows][KP_]; BT: swizzled bf16 [NPB][KP_] (row n holds W[:,n])
#define MB 128
#define NB 128
__launch_bounds__(256)
__global__ void k_mgemm(const ushort_t* __restrict__ A, const ushort_t* __restrict__ BT,
                        float* __restrict__ C, int M, int Nn,
                        const float* __restrict__ bias) {
    __shared__ ushort_t As[MB * 32];
    __shared__ ushort_t Bs[NB * 32];
    int tid = threadIdx.x;
    int lane = tid & 63, wid = tid >> 6;
    int wm = wid >> 1, wn = wid & 1;
    int m0 = blockIdx.x * MB, n0 = blockIdx.y * NB;
    f32x4 acc[4][4];
    #pragma unroll
    for (int mi = 0; mi < 4; mi++)
        #pragma unroll
        for (int ni = 0; ni < 4; ni++)
            acc[mi][ni] = (f32x4){0.f, 0.f, 0.f, 0.f};

    const ushort_t* Ab = A + (size_t)m0 * KP_;
    const ushort_t* Bb = BT + (size_t)n0 * KP_;
    int lr = lane & 15, lg = lane >> 4;

    for (int k0 = 0; k0 < KP_; k0 += 32) {
        #pragma unroll
        for (int i = 0; i < 2; i++) {
            int li = tid + 256 * i;
            int r = li >> 2, u = li & 3;
            gl_lds16(Ab + (size_t)r * KP_ + k0 + u * 8, &As[(size_t)(li & ~63) * 8]);
        }
        #pragma unroll
        for (int i = 0; i < 2; i++) {
            int li = tid + 256 * i;
            int r = li >> 2, u = li & 3;
            gl_lds16(Bb + (size_t)r * KP_ + k0 + u * 8, &Bs[(size_t)(li & ~63) * 8]);
        }
        __syncthreads();
        bf16x8 af[4], bv[4];
        #pragma unroll
        for (int mi = 0; mi < 4; mi++) {
            int rr = wm * 64 + mi * 16 + lr;
            int uu = lg ^ ((rr >> 1) & 3);
            af[mi] = *(const bf16x8*)&As[rr * 32 + uu * 8];
        }
        #pragma unroll
        for (int ni = 0; ni < 4; ni++) {
            int rr = wn * 64 + ni * 16 + lr;
            int uu = lg ^ ((rr >> 1) & 3);
            bv[ni] = *(const bf16x8*)&Bs[rr * 32 + uu * 8];
        }
        #pragma unroll
        for (int mi = 0; mi < 4; mi++)
            #pragma unroll
            for (int ni = 0; ni < 4; ni++)
                acc[mi][ni] = __builtin_amdgcn_mfma_f32_16x16x32_bf16(
                    af[mi], bv[ni], acc[mi][ni], 0, 0, 0);
        __syncthreads();
    }

    #pragma unroll
    for (int ni = 0; ni < 4; ni++) {
        int gn = n0 + wn * 64 + ni * 16 + lr;
        if (gn >= Nn) continue;
        float bvv = bias[gn];
        #pragma unroll
        for (int mi = 0; mi < 4; mi++) {
            #pragma unroll
            for (int t = 0; t < 4; t++) {
                int gm = m0 + wm * 64 + mi * 16 + lg * 4 + t;
                if (gm < M) C[(size_t)gm * Nn + gn] = acc[mi][ni][t] + bvv;
            }
        }
    }
}

// ---------------- generic fp32 GEMM with fused epilogue (small matmuls) ----------------
#define GBM 128
#define GBN 64
#define GBK 16
__launch_bounds__(256)
__global__ void k_gemm(const float* __restrict__ A, const float* __restrict__ Bm,
                       float* __restrict__ C, int M, int Nn, int K,
                       const float* __restrict__ bias, const float* __restrict__ scale,
                       const float* __restrict__ shift, int relu) {
    __shared__ float As[GBM][GBK + 1];
    __shared__ float Bs[GBK][GBN];
    int tid = threadIdx.x;
    int tx = tid & 15, ty = tid >> 4;
    int m0 = blockIdx.x * GBM, n0 = blockIdx.y * GBN;
    float acc[8][4];
    #pragma unroll
    for (int i = 0; i < 8; i++)
        #pragma unroll
        for (int j = 0; j < 4; j++) acc[i][j] = 0.f;

    for (int k0 = 0; k0 < K; k0 += GBK) {
        #pragma unroll
        for (int i = 0; i < 8; i++) {
            int li = tid + i * 256;
            int r = li >> 4, c = li & 15;
            int gm = m0 + r, gk = k0 + c;
            As[r][c] = (gm < M && gk < K) ? A[(size_t)gm * K + gk] : 0.f;
        }
        #pragma unroll
        for (int i = 0; i < 4; i++) {
            int li = tid + i * 256;
            int r = li >> 6, c = li & 63;
            int gk = k0 + r, gn = n0 + c;
            Bs[r][c] = (gk < K && gn < Nn) ? Bm[(size_t)gk * Nn + gn] : 0.f;
        }
        __syncthreads();
        #pragma unroll
        for (int k = 0; k < GBK; k++) {
            float4 b4 = *reinterpret_cast<const float4*>(&Bs[k][4 * tx]);
            #pragma unroll
            for (int i = 0; i < 8; i++) {
                float a = As[ty + 16 * i][k];
                acc[i][0] += a * b4.x;
                acc[i][1] += a * b4.y;
                acc[i][2] += a * b4.z;
                acc[i][3] += a * b4.w;
            }
        }
        __syncthreads();
    }
    #pragma unroll
    for (int i = 0; i < 8; i++) {
        int gm = m0 + ty + 16 * i;
        if (gm >= M) continue;
        #pragma unroll
        for (int j = 0; j < 4; j++) {
            int gn = n0 + 4 * tx + j;
            if (gn >= Nn) continue;
            float v = acc[i][j];
            if (bias) v += bias[gn];
            if (scale) v = v * (scale[gn] * BNS) + shift[gn];
            if (relu) v = fmaxf(v, 0.f);
            C[(size_t)gm * Nn + gn] = v;
        }
    }
}

// ---------------- per-graph segment sums (read swizzled bf16 h) ----------------
__global__ void k_vtmp(const ushort_t* __restrict__ h_bf, const float* __restrict__ vn,
                       const int* __restrict__ rs, float* __restrict__ vtmp) {
    int b = blockIdx.x; int j = threadIdx.x;
    if (j >= H_) return;
    int s = rs[b], e = rs[b + 1];
    int jbase = (j & ~31) | (j & 7);
    int ju = (j >> 3) & 3;
    float acc = 0.f;
    for (int n = s; n < e; n++) {
        int col = jbase | ((ju ^ ((n >> 1) & 3)) << 3);
        acc += b2f(h_bf[(size_t)n * KP_ + col]);
    }
    vtmp[(size_t)b * H_ + j] = acc + vn[(size_t)b * H_ + j];
}

__global__ void k_gmean(const ushort_t* __restrict__ h_bf, const int* __restrict__ rs,
                        float* __restrict__ gm) {
    int b = blockIdx.x; int j = threadIdx.x;
    if (j >= H_) return;
    int s = rs[b], e = rs[b + 1];
    int jbase = (j & ~31) | (j & 7);
    int ju = (j >> 3) & 3;
    float acc = 0.f;
    for (int n = s; n < e; n++) {
        int col = jbase | ((ju ^ ((n >> 1) & 3)) << 3);
        acc += b2f(h_bf[(size_t)n * KP_ + col]);
    }
    int cnt = e - s; if (cnt < 1) cnt = 1;
    gm[(size_t)b * H_ + j] = acc / (float)cnt;
}

// ---------------- edge aggregation + epilogue (writes h_bf swizzled) ------------
__global__ void k_agg(const float* __restrict__ x,
                      ushort_t* __restrict__ h_bf,
                      const int* __restrict__ off, const int* __restrict__ csrc,
                      const int* __restrict__ ceid,
                      const float* __restrict__ ef,
                      const float* __restrict__ We_l, const float* __restrict__ be_l,
                      const float* __restrict__ nrm, const float* __restrict__ invdeg,
                      const float* __restrict__ root_l, const float* __restrict__ gamma_l,
                      const float* __restrict__ beta_l,
                      const float* __restrict__ vn_next, const int* __restrict__ gid,
                      int relu) {
    int n = blockIdx.x; int j = threadIdx.x;
    if (j >= H_) return;
    float wr[16];
    #pragma unroll
    for (int k = 0; k < EF_; k++) wr[k] = We_l[k * H_ + j];
    int s = off[n], e = off[n + 1];
    float nn = nrm[n];
    float bej = be_l[j];
    float acc = 0.f;
    for (int idx = s; idx < e; idx++) {
        int sn = csrc[idx];
        int ed = ceid[idx];
        float en = nn * nrm[sn];
        const float4* ep = (const float4*)&ef[(size_t)ed * EF_];
        float4 e0 = ep[0], e1 = ep[1], e2 = ep[2], e3 = ep[3];
        float ev = bej
            + e0.x * wr[0] + e0.y * wr[1] + e0.z * wr[2] + e0.w * wr[3]
            + e1.x * wr[4] + e1.y * wr[5] + e1.z * wr[6] + e1.w * wr[7]
            + e2.x * wr[8] + e2.y * wr[9] + e2.z * wr[10] + e2.w * wr[11]
            + e3.x * wr[12] + e3.y * wr[13] + e3.z * wr[14] + e3.w * wr[15];
        float msg = x[(size_t)sn * H_ + j] + ev;
        acc += en * fmaxf(msg, 0.f);
    }
    float v = acc + fmaxf(x[(size_t)n * H_ + j] + root_l[j], 0.f) * invdeg[n];
    v = v * (gamma_l[j] * BNS) + beta_l[j];
    if (relu) v = fmaxf(v, 0.f);
    if (vn_next) v += vn_next[(size_t)gid[n] * H_ + j];
    int u = ((j >> 3) & 3) ^ ((n >> 1) & 3);
    int col = (j & ~31) | (u << 3) | (j & 7);
    h_bf[(size_t)n * KP_ + col] = f2b(v);
}

// ---------------- launch ----------------
extern "C" void kernel_launch(void* const* d_in, const int* in_sizes, int n_in,
                              void* d_out, int out_size, void* d_ws, size_t ws_size,
                              hipStream_t stream) {
    const int* node_types = (const int*)d_in[0];
    const int* src        = (const int*)d_in[1];
    const int* dst        = (const int*)d_in[2];
    const int* graph_ids  = (const int*)d_in[3];
    const float* edge_feats = (const float*)d_in[4];
    const float* node_emb   = (const float*)d_in[5];
    const float* Wn   = (const float*)d_in[6];
    const float* bn   = (const float*)d_in[7];
    const float* We   = (const float*)d_in[8];
    const float* be   = (const float*)d_in[9];
    const float* root = (const float*)d_in[10];
    const float* gamma = (const float*)d_in[11];
    const float* beta  = (const float*)d_in[12];
    const float* vn_emb = (const float*)d_in[13];
    const float* W1  = (const float*)d_in[14];
    const float* b1  = (const float*)d_in[15];
    const float* g1  = (const float*)d_in[16];
    const float* be1 = (const float*)d_in[17];
    const float* W2  = (const float*)d_in[18];
    const float* b2  = (const float*)d_in[19];
    const float* g2  = (const float*)d_in[20];
    const float* be2 = (const float*)d_in[21];
    const float* pW  = (const float*)d_in[22];
    const float* pb  = (const float*)d_in[23];
    float* out = (float*)d_out;

    // workspace carve-up (~200 MB total; R1's working layout proved >=253 MB available)
    char* p = (char*)d_ws;
    auto alloc = [&](size_t bytes) { void* q = (void*)p; p += (bytes + 255) & ~(size_t)255; return q; };
    float* x     = (float*)alloc((size_t)N_ * H_ * 4);            // 120 MB
    ushort_t* h_bf = (ushort_t*)alloc((size_t)MPAD * KP_ * 2);    //  64 MB
    ushort_t* WnT  = (ushort_t*)alloc((size_t)L_ * NPB * KP_ * 2);// 1.2 MB
    float* vn    = (float*)alloc((size_t)B_ * H_ * 4);
    float* vtmp  = (float*)alloc((size_t)B_ * H_ * 4);
    float* z     = (float*)alloc((size_t)B_ * 2 * H_ * 4);
    float* nrm   = (float*)alloc((size_t)N_ * 4);
    float* invdeg= (float*)alloc((size_t)N_ * 4);
    int* degi    = (int*)alloc((size_t)N_ * 4);
    int* csr_off = (int*)alloc((size_t)(N_ + 1) * 4);
    int* cursor  = (int*)alloc((size_t)N_ * 4);
    int* csr_eid = (int*)alloc((size_t)E_ * 4);
    int* csr_src = (int*)alloc((size_t)E_ * 4);
    int* rs      = (int*)alloc((size_t)(B_ + 1) * 4);
    int* partial = (int*)alloc((size_t)128 * 4);

    const int SCAN_NB = (N_ + 1023) / 1024;  // 98

    // degree histogram + norms
    hipMemsetAsync(degi, 0, (size_t)N_ * 4, stream);
    hipMemsetAsync(h_bf, 0, (size_t)MPAD * KP_ * 2, stream);  // pad rows/cols stay zero
    k_hist<<<(E_ + 255) / 256, 256, 0, stream>>>(dst, degi, E_);
    k_norm<<<(N_ + 255) / 256, 256, 0, stream>>>(degi, nrm, invdeg, N_);

    // CSR offsets = exclusive scan of degi
    k_scan1<<<SCAN_NB, 1024, 0, stream>>>(degi, csr_off, partial, N_);
    k_scan2<<<1, 1, 0, stream>>>(partial, SCAN_NB, csr_off + N_);
    k_scan3<<<SCAN_NB, 1024, 0, stream>>>(csr_off, partial, N_);
    hipMemcpyAsync(cursor, csr_off, (size_t)N_ * 4, hipMemcpyDeviceToDevice, stream);
    k_scatter<<<(E_ + 255) / 256, 256, 0, stream>>>(dst, src, cursor, csr_eid, csr_src, E_);

    // graph segment boundaries (graph_ids sorted)
    k_rowstart<<<(B_ + 1 + 255) / 256, 256, 0, stream>>>(graph_ids, rs, N_, B_);

    // weights -> bf16 transposed swizzled
    k_convWnT<<<(L_ * NPB * (KP_ / 8) + 255) / 256, 256, 0, stream>>>(Wn, WnT);

    // h = node_emb[nt] + vn_emb (layer-0 vn broadcast fused); vn = vn_emb
    k_hinit<<<N_, 320, 0, stream>>>(node_types, node_emb, vn_emb, h_bf);
    k_vninit<<<B_, 320, 0, stream>>>(vn_emb, vn);

    dim3 gmm(MPAD / MB, (H_ + NB - 1) / NB);                   // 782 x 3
    dim3 gm1((B_ + GBM - 1) / GBM, (2 * H_ + GBN - 1) / GBN);  // 16 x 10
    dim3 gm2((B_ + GBM - 1) / GBM, (H_ + GBN - 1) / GBN);      // 16 x 5
    dim3 gh((B_ + GBM - 1) / GBM, (T_ + GBN - 1) / GBN);       // 16 x 2

    for (int l = 0; l < L_; l++) {
        // x = h @ Wn[l] + bn[l]   (bf16 MFMA)
        k_mgemm<<<gmm, 256, 0, stream>>>(h_bf, WnT + (size_t)l * NPB * KP_, x,
                                         N_, H_, bn + (size_t)l * H_);
        if (l < L_ - 1) {
            // vtmp = segsum(h) + vn ; z = relu(bn1(vtmp@W1+b1)) ; vn = relu(bn2(z@W2+b2))
            k_vtmp<<<B_, 320, 0, stream>>>(h_bf, vn, rs, vtmp);
            k_gemm<<<gm1, 256, 0, stream>>>(vtmp, W1 + (size_t)l * H_ * 2 * H_, z,
                                            B_, 2 * H_, H_,
                                            b1 + (size_t)l * 2 * H_,
                                            g1 + (size_t)l * 2 * H_,
                                            be1 + (size_t)l * 2 * H_, 1);
            k_gemm<<<gm2, 256, 0, stream>>>(z, W2 + (size_t)l * 2 * H_ * H_, vn,
                                            B_, H_, 2 * H_,
                                            b2 + (size_t)l * H_,
                                            g2 + (size_t)l * H_,
                                            be2 + (size_t)l * H_, 1);
        }
        // h = bn(agg + relu(x+root)*invdeg) (+relu/+vn_next if l<L-1)
        k_agg<<<N_, 320, 0, stream>>>(x, h_bf, csr_off, csr_src, csr_eid,
                                      edge_feats,
                                      We + (size_t)l * EF_ * H_, be + (size_t)l * H_,
                                      nrm, invdeg,
                                      root + (size_t)l * H_,
                                      gamma + (size_t)l * H_, beta + (size_t)l * H_,
                                      (l < L_ - 1) ? vn : nullptr, graph_ids,
                                      (l < L_ - 1) ? 1 : 0);
    }

    // readout: gmean -> head
    k_gmean<<<B_, 320, 0, stream>>>(h_bf, rs, vtmp);
    k_gemm<<<gh, 256, 0, stream>>>(vtmp, pW, out, B_, T_, H_, pb, nullptr, nullptr, 0);
}

// Round 4
// 2274.457 us; speedup vs baseline: 2.8674x; 1.4449x over previous
//
#include <hip/hip_runtime.h>
#include <hip/hip_bf16.h>

// Problem constants (fixed by the reference)
#define N_ 100000
#define MPAD 100096          // 782 * 128
#define E_ 400000
#define B_ 2048
#define H_ 300
#define KP_ 320              // H padded to mult of 32
#define L_ 5
#define EF_ 16
#define T_ 128
#define BNS 0.9999950000374997f  // 1/sqrt(1+1e-5)

typedef unsigned short ushort_t;
typedef short bf16x8 __attribute__((ext_vector_type(8)));
typedef float f32x4 __attribute__((ext_vector_type(4)));

__device__ __forceinline__ ushort_t f2b(float v) {
    unsigned u = __float_as_uint(v);
    unsigned r = (u + 0x7FFFu + ((u >> 16) & 1u)) >> 16;
    return (ushort_t)r;
}

__device__ __forceinline__ float b2f(ushort_t u) {
    return __uint_as_float(((unsigned)u) << 16);
}

__device__ __forceinline__ void gl_lds16(const void* g, void* l) {
    __builtin_amdgcn_global_load_lds(
        (const __attribute__((address_space(1))) void*)g,
        (__attribute__((address_space(3))) void*)l, 16, 0, 0);
}

// swizzled column for logical (row r, col j) in a [rows][KPv] bf16 buffer
__device__ __forceinline__ int swzcol(int r, int j) {
    int u = ((j >> 3) & 3) ^ ((r >> 1) & 3);
    return (j & ~31) | (u << 3) | (j & 7);
}

// ---------------- CSR build ----------------
__global__ void k_hist(const int* __restrict__ dst, int* __restrict__ degi, int E) {
    int e = blockIdx.x * blockDim.x + threadIdx.x;
    if (e < E) atomicAdd(&degi[dst[e]], 1);
}

__global__ void k_norm(const int* __restrict__ degi, float* __restrict__ nrm,
                       float* __restrict__ invdeg, int N) {
    int n = blockIdx.x * blockDim.x + threadIdx.x;
    if (n < N) {
        float d = (float)degi[n] + 1.0f;
        nrm[n] = 1.0f / sqrtf(d);
        invdeg[n] = 1.0f / d;
    }
}

__global__ void k_scan1(const int* __restrict__ in, int* __restrict__ out,
                        int* __restrict__ partial, int N) {
    __shared__ int s[1024];
    int i = blockIdx.x * 1024 + threadIdx.x;
    int v = (i < N) ? in[i] : 0;
    s[threadIdx.x] = v;
    __syncthreads();
    for (int off = 1; off < 1024; off <<= 1) {
        int t = (threadIdx.x >= off) ? s[threadIdx.x - off] : 0;
        __syncthreads();
        s[threadIdx.x] += t;
        __syncthreads();
    }
    if (i < N) out[i] = s[threadIdx.x] - v;  // exclusive
    if (threadIdx.x == 1023) partial[blockIdx.x] = s[1023];
}

__global__ void k_scan2(int* __restrict__ partial, int nb, int* __restrict__ totalOut) {
    if (blockIdx.x == 0 && threadIdx.x == 0) {
        int run = 0;
        for (int i = 0; i < nb; i++) { int v = partial[i]; partial[i] = run; run += v; }
        *totalOut = run;
    }
}

__global__ void k_scan3(int* __restrict__ out, const int* __restrict__ partial, int N) {
    int i = blockIdx.x * 1024 + threadIdx.x;
    if (i < N) out[i] += partial[blockIdx.x];
}

// scatter edges into CSR order; pre-gather edge feats + per-edge norm
__global__ void k_scatter(const int* __restrict__ dst, const int* __restrict__ src,
                          const float* __restrict__ ef, const float* __restrict__ nrm,
                          int* __restrict__ cursor, int* __restrict__ csrc,
                          float* __restrict__ ef_csr, float* __restrict__ en_csr, int E) {
    int e = blockIdx.x * blockDim.x + threadIdx.x;
    if (e >= E) return;
    int d = dst[e], s = src[e];
    int pos = atomicAdd(&cursor[d], 1);
    csrc[pos] = s;
    en_csr[pos] = nrm[s] * nrm[d];
    const float4* ep = (const float4*)&ef[(size_t)e * EF_];
    float4* op = (float4*)&ef_csr[(size_t)pos * EF_];
    op[0] = ep[0]; op[1] = ep[1]; op[2] = ep[2]; op[3] = ep[3];
}

__global__ void k_rowstart(const int* __restrict__ gid, int* __restrict__ rs, int N, int B) {
    int b = blockIdx.x * blockDim.x + threadIdx.x;
    if (b <= B) {
        int lo = 0, hi = N;
        while (lo < hi) { int mid = (lo + hi) >> 1; if (gid[mid] < b) lo = mid + 1; else hi = mid; }
        rs[b] = lo;
    }
}

// ---------------- init ----------------
__global__ void k_hinit(const int* __restrict__ nt, const float* __restrict__ emb,
                        const float* __restrict__ vn_emb,
                        ushort_t* __restrict__ h_bf) {
    int n = blockIdx.x; int j = threadIdx.x;
    if (j >= H_) return;
    float v = emb[(size_t)nt[n] * H_ + j] + vn_emb[j];
    h_bf[(size_t)n * KP_ + swzcol(n, j)] = f2b(v);
}

__global__ void k_vninit(const float* __restrict__ vn_emb, float* __restrict__ vn) {
    int b = blockIdx.x; int j = threadIdx.x;
    if (j >= H_) return;
    vn[(size_t)b * H_ + j] = vn_emb[j];
}

// generic weight conversion: WT[l][n][k] = W[l][k][n], bf16, zero-padded, swizzled
__global__ void k_convW(const float* __restrict__ W, ushort_t* __restrict__ WT,
                        int nl, int K, int Nout, int KPv, int NPBv) {
    int UPR = KPv / 8;
    int tot = nl * NPBv * UPR;
    int idx = blockIdx.x * 256 + threadIdx.x;
    if (idx >= tot) return;
    int l = idx / (NPBv * UPR); int r = idx % (NPBv * UPR);
    int n = r / UPR; int ku = r % UPR;
    int k0 = ku * 8;
    int swz = (ku & 3) ^ ((n >> 1) & 3);
    size_t d = ((size_t)l * NPBv + n) * KPv + (size_t)(k0 & ~31) + swz * 8;
    #pragma unroll
    for (int i = 0; i < 8; i++) {
        int k = k0 + i;
        float v = (k < K && n < Nout) ? W[((size_t)l * K + k) * Nout + n] : 0.f;
        WT[d + i] = f2b(v);
    }
}

// ---------------- unified bf16 MFMA GEMM ----------------
// C = epilogue(A[M,KP] @ BT[*,KP]^T + bias), KP runtime (mult of 32).
// A, BT pre-swizzled bf16. Output: Cf (fp32, stride ldf) or Cb (bf16 swizzled, stride ldb).
#define MB 128
#define NB 128
__launch_bounds__(256)
__global__ void k_bgemm(const ushort_t* __restrict__ A, const ushort_t* __restrict__ BT,
                        int M, int Nn, int KP,
                        const float* __restrict__ bias, const float* __restrict__ scale,
                        const float* __restrict__ shift, int relu,
                        float* __restrict__ Cf, int ldf,
                        ushort_t* __restrict__ Cb, int ldb) {
    __shared__ ushort_t As[MB * 32];
    __shared__ ushort_t Bs[NB * 32];
    int tid = threadIdx.x;
    int lane = tid & 63, wid = tid >> 6;
    int wm = wid >> 1, wn = wid & 1;
    int m0 = blockIdx.x * MB, n0 = blockIdx.y * NB;
    f32x4 acc[4][4];
    #pragma unroll
    for (int mi = 0; mi < 4; mi++)
        #pragma unroll
        for (int ni = 0; ni < 4; ni++)
            acc[mi][ni] = (f32x4){0.f, 0.f, 0.f, 0.f};

    const ushort_t* Ab = A + (size_t)m0 * KP;
    const ushort_t* Bb = BT + (size_t)n0 * KP;
    int lr = lane & 15, lg = lane >> 4;

    for (int k0 = 0; k0 < KP; k0 += 32) {
        #pragma unroll
        for (int i = 0; i < 2; i++) {
            int li = tid + 256 * i;
            int r = li >> 2, u = li & 3;
            gl_lds16(Ab + (size_t)r * KP + k0 + u * 8, &As[(size_t)(li & ~63) * 8]);
        }
        #pragma unroll
        for (int i = 0; i < 2; i++) {
            int li = tid + 256 * i;
            int r = li >> 2, u = li & 3;
            gl_lds16(Bb + (size_t)r * KP + k0 + u * 8, &Bs[(size_t)(li & ~63) * 8]);
        }
        __syncthreads();
        bf16x8 af[4], bv[4];
        #pragma unroll
        for (int mi = 0; mi < 4; mi++) {
            int rr = wm * 64 + mi * 16 + lr;
            int uu = lg ^ ((rr >> 1) & 3);
            af[mi] = *(const bf16x8*)&As[rr * 32 + uu * 8];
        }
        #pragma unroll
        for (int ni = 0; ni < 4; ni++) {
            int rr = wn * 64 + ni * 16 + lr;
            int uu = lg ^ ((rr >> 1) & 3);
            bv[ni] = *(const bf16x8*)&Bs[rr * 32 + uu * 8];
        }
        #pragma unroll
        for (int mi = 0; mi < 4; mi++)
            #pragma unroll
            for (int ni = 0; ni < 4; ni++)
                acc[mi][ni] = __builtin_amdgcn_mfma_f32_16x16x32_bf16(
                    af[mi], bv[ni], acc[mi][ni], 0, 0, 0);
        __syncthreads();
    }

    #pragma unroll
    for (int ni = 0; ni < 4; ni++) {
        int gn = n0 + wn * 64 + ni * 16 + lr;
        if (gn >= Nn) continue;
        float bvv = bias[gn];
        float sc = scale ? scale[gn] * BNS : 0.f;
        float sh = shift ? shift[gn] : 0.f;
        #pragma unroll
        for (int mi = 0; mi < 4; mi++) {
            #pragma unroll
            for (int t = 0; t < 4; t++) {
                int gm = m0 + wm * 64 + mi * 16 + lg * 4 + t;
                if (gm >= M) continue;
                float v = acc[mi][ni][t] + bvv;
                if (scale) v = v * sc + sh;
                if (relu) v = fmaxf(v, 0.f);
                if (Cf) Cf[(size_t)gm * ldf + gn] = v;
                else    Cb[(size_t)gm * ldb + swzcol(gm, gn)] = f2b(v);
            }
        }
    }
}

// ---------------- fp32 GEMM (head only) ----------------
#define GBM 128
#define GBN 64
#define GBK 16
__launch_bounds__(256)
__global__ void k_gemm(const float* __restrict__ A, const float* __restrict__ Bm,
                       float* __restrict__ C, int M, int Nn, int K,
                       const float* __restrict__ bias) {
    __shared__ float As[GBM][GBK + 1];
    __shared__ float Bs[GBK][GBN];
    int tid = threadIdx.x;
    int tx = tid & 15, ty = tid >> 4;
    int m0 = blockIdx.x * GBM, n0 = blockIdx.y * GBN;
    float acc[8][4];
    #pragma unroll
    for (int i = 0; i < 8; i++)
        #pragma unroll
        for (int j = 0; j < 4; j++) acc[i][j] = 0.f;

    for (int k0 = 0; k0 < K; k0 += GBK) {
        #pragma unroll
        for (int i = 0; i < 8; i++) {
            int li = tid + i * 256;
            int r = li >> 4, c = li & 15;
            int gm = m0 + r, gk = k0 + c;
            As[r][c] = (gm < M && gk < K) ? A[(size_t)gm * K + gk] : 0.f;
        }
        #pragma unroll
        for (int i = 0; i < 4; i++) {
            int li = tid + i * 256;
            int r = li >> 6, c = li & 63;
            int gk = k0 + r, gn = n0 + c;
            Bs[r][c] = (gk < K && gn < Nn) ? Bm[(size_t)gk * Nn + gn] : 0.f;
        }
        __syncthreads();
        #pragma unroll
        for (int k = 0; k < GBK; k++) {
            float4 b4 = *reinterpret_cast<const float4*>(&Bs[k][4 * tx]);
            #pragma unroll
            for (int i = 0; i < 8; i++) {
                float a = As[ty + 16 * i][k];
                acc[i][0] += a * b4.x;
                acc[i][1] += a * b4.y;
                acc[i][2] += a * b4.z;
                acc[i][3] += a * b4.w;
            }
        }
        __syncthreads();
    }
    #pragma unroll
    for (int i = 0; i < 8; i++) {
        int gm = m0 + ty + 16 * i;
        if (gm >= M) continue;
        #pragma unroll
        for (int j = 0; j < 4; j++) {
            int gn = n0 + 4 * tx + j;
            if (gn >= Nn) continue;
            C[(size_t)gm * Nn + gn] = acc[i][j] + bias[gn];
        }
    }
}

// ---------------- per-graph segment sums ----------------
// vtmp_bf = swizzled bf16 of (segsum(h) + vn)
__global__ void k_vtmp(const ushort_t* __restrict__ h_bf, const float* __restrict__ vn,
                       const int* __restrict__ rs, ushort_t* __restrict__ vtmp_bf) {
    int b = blockIdx.x; int j = threadIdx.x;
    if (j >= H_) return;
    int s = rs[b], e = rs[b + 1];
    int jbase = (j & ~31) | (j & 7);
    int ju = (j >> 3) & 3;
    float acc = 0.f;
    for (int n = s; n < e; n++) {
        int col = jbase | ((ju ^ ((n >> 1) & 3)) << 3);
        acc += b2f(h_bf[(size_t)n * KP_ + col]);
    }
    vtmp_bf[(size_t)b * KP_ + swzcol(b, j)] = f2b(acc + vn[(size_t)b * H_ + j]);
}

__global__ void k_gmean(const ushort_t* __restrict__ h_bf, const int* __restrict__ rs,
                        float* __restrict__ gm) {
    int b = blockIdx.x; int j = threadIdx.x;
    if (j >= H_) return;
    int s = rs[b], e = rs[b + 1];
    int jbase = (j & ~31) | (j & 7);
    int ju = (j >> 3) & 3;
    float acc = 0.f;
    for (int n = s; n < e; n++) {
        int col = jbase | ((ju ^ ((n >> 1) & 3)) << 3);
        acc += b2f(h_bf[(size_t)n * KP_ + col]);
    }
    int cnt = e - s; if (cnt < 1) cnt = 1;
    gm[(size_t)b * H_ + j] = acc / (float)cnt;
}

// ---------------- edge aggregation + epilogue (bf16 x gather, writes h_bf) ------------
__global__ void k_agg(const ushort_t* __restrict__ x_bf,
                      ushort_t* __restrict__ h_bf,
                      const int* __restrict__ off, const int* __restrict__ csrc,
                      const float* __restrict__ ef_csr, const float* __restrict__ en_csr,
                      const float* __restrict__ We_l, const float* __restrict__ be_l,
                      const float* __restrict__ invdeg,
                      const float* __restrict__ root_l, const float* __restrict__ gamma_l,
                      const float* __restrict__ beta_l,
                      const float* __restrict__ vn_next, const int* __restrict__ gid,
                      int relu) {
    int n = blockIdx.x; int j = threadIdx.x;
    if (j >= H_) return;
    float wr[16];
    #pragma unroll
    for (int k = 0; k < EF_; k++) wr[k] = We_l[k * H_ + j];
    int s = off[n], e = off[n + 1];
    int jbase = (j & ~31) | (j & 7);
    int ju = (j >> 3) & 3;
    float bej = be_l[j];
    float acc = 0.f;
    for (int idx = s; idx < e; idx++) {
        int sn = csrc[idx];
        float en = en_csr[idx];
        const float4* ep = (const float4*)&ef_csr[(size_t)idx * EF_];
        float4 e0 = ep[0], e1 = ep[1], e2 = ep[2], e3 = ep[3];
        float ev = bej
            + e0.x * wr[0] + e0.y * wr[1] + e0.z * wr[2] + e0.w * wr[3]
            + e1.x * wr[4] + e1.y * wr[5] + e1.z * wr[6] + e1.w * wr[7]
            + e2.x * wr[8] + e2.y * wr[9] + e2.z * wr[10] + e2.w * wr[11]
            + e3.x * wr[12] + e3.y * wr[13] + e3.z * wr[14] + e3.w * wr[15];
        int xcol = jbase | ((ju ^ ((sn >> 1) & 3)) << 3);
        float msg = b2f(x_bf[(size_t)sn * KP_ + xcol]) + ev;
        acc += en * fmaxf(msg, 0.f);
    }
    int ncol = jbase | ((ju ^ ((n >> 1) & 3)) << 3);
    float xn = b2f(x_bf[(size_t)n * KP_ + ncol]);
    float v = acc + fmaxf(xn + root_l[j], 0.f) * invdeg[n];
    v = v * (gamma_l[j] * BNS) + beta_l[j];
    if (relu) v = fmaxf(v, 0.f);
    if (vn_next) v += vn_next[(size_t)gid[n] * H_ + j];
    h_bf[(size_t)n * KP_ + ncol] = f2b(v);
}

// ---------------- launch ----------------
extern "C" void kernel_launch(void* const* d_in, const int* in_sizes, int n_in,
                              void* d_out, int out_size, void* d_ws, size_t ws_size,
                              hipStream_t stream) {
    const int* node_types = (const int*)d_in[0];
    const int* src        = (const int*)d_in[1];
    const int* dst        = (const int*)d_in[2];
    const int* graph_ids  = (const int*)d_in[3];
    const float* edge_feats = (const float*)d_in[4];
    const float* node_emb   = (const float*)d_in[5];
    const float* Wn   = (const float*)d_in[6];
    const float* bn   = (const float*)d_in[7];
    const float* We   = (const float*)d_in[8];
    const float* be   = (const float*)d_in[9];
    const float* root = (const float*)d_in[10];
    const float* gamma = (const float*)d_in[11];
    const float* beta  = (const float*)d_in[12];
    const float* vn_emb = (const float*)d_in[13];
    const float* W1  = (const float*)d_in[14];
    const float* b1  = (const float*)d_in[15];
    const float* g1  = (const float*)d_in[16];
    const float* be1 = (const float*)d_in[17];
    const float* W2  = (const float*)d_in[18];
    const float* b2  = (const float*)d_in[19];
    const float* g2  = (const float*)d_in[20];
    const float* be2 = (const float*)d_in[21];
    const float* pW  = (const float*)d_in[22];
    const float* pb  = (const float*)d_in[23];
    float* out = (float*)d_out;

    // workspace carve-up (~172 MB; R1 proved >=253 MB available)
    char* p = (char*)d_ws;
    auto alloc = [&](size_t bytes) { void* q = (void*)p; p += (bytes + 255) & ~(size_t)255; return q; };
    ushort_t* h_bf   = (ushort_t*)alloc((size_t)MPAD * KP_ * 2);   // 64 MB
    ushort_t* x_bf   = (ushort_t*)alloc((size_t)MPAD * KP_ * 2);   // 64 MB
    ushort_t* WnT    = (ushort_t*)alloc((size_t)L_ * 384 * KP_ * 2);
    ushort_t* W1T    = (ushort_t*)alloc((size_t)4 * 640 * KP_ * 2);
    ushort_t* W2T    = (ushort_t*)alloc((size_t)4 * 384 * 640 * 2);
    ushort_t* vtmp_bf= (ushort_t*)alloc((size_t)B_ * KP_ * 2);
    ushort_t* z_bf   = (ushort_t*)alloc((size_t)B_ * 640 * 2);
    float* vn    = (float*)alloc((size_t)B_ * H_ * 4);
    float* gmean = (float*)alloc((size_t)B_ * H_ * 4);
    float* nrm   = (float*)alloc((size_t)N_ * 4);
    float* invdeg= (float*)alloc((size_t)N_ * 4);
    int* degi    = (int*)alloc((size_t)N_ * 4);
    int* csr_off = (int*)alloc((size_t)(N_ + 1) * 4);
    int* cursor  = (int*)alloc((size_t)N_ * 4);
    int* csr_src = (int*)alloc((size_t)E_ * 4);
    float* ef_csr= (float*)alloc((size_t)E_ * EF_ * 4);            // 25.6 MB
    float* en_csr= (float*)alloc((size_t)E_ * 4);
    int* rs      = (int*)alloc((size_t)(B_ + 1) * 4);
    int* partial = (int*)alloc((size_t)128 * 4);

    const int SCAN_NB = (N_ + 1023) / 1024;  // 98

    // degree histogram + norms
    hipMemsetAsync(degi, 0, (size_t)N_ * 4, stream);
    k_hist<<<(E_ + 255) / 256, 256, 0, stream>>>(dst, degi, E_);
    k_norm<<<(N_ + 255) / 256, 256, 0, stream>>>(degi, nrm, invdeg, N_);

    // CSR offsets = exclusive scan of degi
    k_scan1<<<SCAN_NB, 1024, 0, stream>>>(degi, csr_off, partial, N_);
    k_scan2<<<1, 1, 0, stream>>>(partial, SCAN_NB, csr_off + N_);
    k_scan3<<<SCAN_NB, 1024, 0, stream>>>(csr_off, partial, N_);
    hipMemcpyAsync(cursor, csr_off, (size_t)N_ * 4, hipMemcpyDeviceToDevice, stream);
    k_scatter<<<(E_ + 255) / 256, 256, 0, stream>>>(dst, src, edge_feats, nrm,
                                                    cursor, csr_src, ef_csr, en_csr, E_);

    // graph segment boundaries (graph_ids sorted)
    k_rowstart<<<(B_ + 1 + 255) / 256, 256, 0, stream>>>(graph_ids, rs, N_, B_);

    // weights -> bf16 transposed swizzled
    k_convW<<<(L_ * 384 * (KP_ / 8) + 255) / 256, 256, 0, stream>>>(Wn, WnT, L_, H_, H_, KP_, 384);
    k_convW<<<(4 * 640 * (KP_ / 8) + 255) / 256, 256, 0, stream>>>(W1, W1T, 4, H_, 2 * H_, KP_, 640);
    k_convW<<<(4 * 384 * (640 / 8) + 255) / 256, 256, 0, stream>>>(W2, W2T, 4, 2 * H_, H_, 640, 384);

    // h = node_emb[nt] + vn_emb; vn = vn_emb
    k_hinit<<<N_, 320, 0, stream>>>(node_types, node_emb, vn_emb, h_bf);
    k_vninit<<<B_, 320, 0, stream>>>(vn_emb, vn);

    dim3 gx(MPAD / MB, 3);    // x GEMM: 782 x 3
    dim3 gz(B_ / MB, 5);      // z GEMM: 16 x 5
    dim3 gv(B_ / MB, 3);      // vn GEMM: 16 x 3
    dim3 gh((B_ + GBM - 1) / GBM, (T_ + GBN - 1) / GBN);  // head: 16 x 2

    for (int l = 0; l < L_; l++) {
        // x = h @ Wn[l] + bn[l]  -> bf16 swizzled
        k_bgemm<<<gx, 256, 0, stream>>>(h_bf, WnT + (size_t)l * 384 * KP_,
                                        N_, H_, KP_, bn + (size_t)l * H_,
                                        nullptr, nullptr, 0,
                                        nullptr, 0, x_bf, KP_);
        if (l < L_ - 1) {
            k_vtmp<<<B_, 320, 0, stream>>>(h_bf, vn, rs, vtmp_bf);
            // z = relu(bn1(vtmp @ W1 + b1)) -> bf16 swizzled [B][640]
            k_bgemm<<<gz, 256, 0, stream>>>(vtmp_bf, W1T + (size_t)l * 640 * KP_,
                                            B_, 2 * H_, KP_, b1 + (size_t)l * 2 * H_,
                                            g1 + (size_t)l * 2 * H_, be1 + (size_t)l * 2 * H_, 1,
                                            nullptr, 0, z_bf, 640);
            // vn = relu(bn2(z @ W2 + b2)) -> fp32 [B][300]
            k_bgemm<<<gv, 256, 0, stream>>>(z_bf, W2T + (size_t)l * 384 * 640,
                                            B_, H_, 640, b2 + (size_t)l * H_,
                                            g2 + (size_t)l * H_, be2 + (size_t)l * H_, 1,
                                            vn, H_, nullptr, 0);
        }
        // h = bn(agg + relu(x+root)*invdeg) (+relu/+vn_next if l<L-1)
        k_agg<<<N_, 320, 0, stream>>>(x_bf, h_bf, csr_off, csr_src,
                                      ef_csr, en_csr,
                                      We + (size_t)l * EF_ * H_, be + (size_t)l * H_,
                                      invdeg,
                                      root + (size_t)l * H_,
                                      gamma + (size_t)l * H_, beta + (size_t)l * H_,
                                      (l < L_ - 1) ? vn : nullptr, graph_ids,
                                      (l < L_ - 1) ? 1 : 0);
    }

    // readout: gmean (fp32) -> head (fp32)
    k_gmean<<<B_, 320, 0, stream>>>(h_bf, rs, gmean);
    k_gemm<<<gh, 256, 0, stream>>>(gmean, pW, out, B_, T_, H_, pb);
}